// Round 17
// baseline (178.603 us; speedup 1.0000x reference)
//
#include <hip/hip_runtime.h>
#include <hip/hip_bf16.h>
#include <stdint.h>

#define BM 128
#define BN 128

typedef __attribute__((ext_vector_type(8))) short bf16x8;
typedef __attribute__((ext_vector_type(4))) float f32x4;
typedef __attribute__((ext_vector_type(4))) uint32_t u32x4;

__device__ __forceinline__ uint32_t pk2(float lo, float hi) {
  union { __hip_bfloat162 h; uint32_t u; } un;
  un.h = __float22bfloat162_rn(make_float2(lo, hi));  // v_cvt_pk_bf16_f32
  return un.u;
}
__device__ __forceinline__ uint16_t bfc(float f) {     // 1-op f32->bf16 RNE
  return (uint16_t)(pk2(f, f) & 0xFFFFu);
}
__device__ __forceinline__ float bf2f(uint16_t s) {
  union { uint32_t u; float f; } v; v.u = ((uint32_t)s) << 16;
  return v.f;
}
__device__ __forceinline__ void gload_lds16(const void* g, void* l) {
  __builtin_amdgcn_global_load_lds((const __attribute__((address_space(1))) void*)g,
                                   (__attribute__((address_space(3))) void*)l, 16, 0, 0);
}
// bijective XCD-chunk swizzle (m204)
__device__ __forceinline__ int xcd_swz(int d, int n) {
  const int q = n >> 3, r = n & 7, x = d & 7, i = d >> 3;
  return (x < r ? x * (q + 1) : r * (q + 1) + (x - r) * q) + i;
}

enum { E_PLAIN16 = 0, E_EDGE = 1, E_NODE = 2, E_PRED = 3 };

struct GemmArgs {
  const uint16_t* Ab; int lda;   // bf16 A (gemm_lds_k)
  const float* Af;               // fp32 A, lda=512 (gemm_reg_k)
  const int* gidx;               // optional row gather
  const uint16_t* B0;            // B^T bf16 [N][K]; out cols < 512
  const uint16_t* B1;            // out cols >= 512
  int K;
  int nwg, ncol;                 // grid decomposition (col-fastest)
  uint16_t* C16; int ldc;        // bf16 output
  const float* bias;
  const float* wattn;
  const int* src; const int* dst; const int* toe;
  const uint16_t* A13;           // bf16 [4096][1024]
  const uint16_t* VISB;          // bf16 [4096][512] (E_EDGE msg fold)
  const uint16_t* U13;           // bf16 [4096][1024]
  uint16_t* EF;                  // MSG bf16 [61440][512]
  float* AATT;                   // attn partials [61440]
  float* OUT;                    // pred fp32 [3840][512]
};

// ---- shared epilogue, 8-wave layout: wave (wm,wn) owns rows wm*64+, cols wn*32+ ----
// C/D frag: col = lane&15, row = (lane>>4)*4 + reg
template <int EPI>
__device__ __forceinline__ void gemm_epilogue(const GemmArgs& g, f32x4 (&acc)[4][2],
                                              int m0, int n0g, int wm, int wn,
                                              int lr, int lg, int vb,
                                              const short* a13s, const short* viss) {
  const int rbase = m0 + wm * 64;
  const int cbase = n0g + wn * 32;
  if constexpr (EPI == E_PLAIN16) {
#pragma unroll
    for (int m = 0; m < 4; ++m)
#pragma unroll
      for (int r = 0; r < 4; ++r) {
        const int row = rbase + m * 16 + lg * 4 + r;
#pragma unroll
        for (int n = 0; n < 2; ++n)
          g.C16[(size_t)row * g.ldc + cbase + n * 16 + lr] = bfc(acc[m][n][r]);
      }
  } else if constexpr (EPI == E_NODE) {
#pragma unroll
    for (int m = 0; m < 4; ++m)
#pragma unroll
      for (int r = 0; r < 4; ++r) {
        const int row = rbase + m * 16 + lg * 4 + r;
#pragma unroll
        for (int n = 0; n < 2; ++n) {
          const int col = cbase + n * 16 + lr;
          g.C16[(size_t)row * g.ldc + col] = bfc(fmaxf(acc[m][n][r] + g.bias[col], 0.f));
        }
      }
  } else if constexpr (EPI == E_EDGE) {
    float bv[2], wv[2]; int lc[2];
#pragma unroll
    for (int n = 0; n < 2; ++n) {
      lc[n] = wn * 32 + n * 16 + lr;          // col within block's 128
      bv[n] = g.bias[n0g + lc[n]];
      wv[n] = g.wattn[n0g + lc[n]];
    }
#pragma unroll
    for (int m = 0; m < 4; ++m)
#pragma unroll
      for (int r = 0; r < 4; ++r) {
        const int e = rbase + m * 16 + lg * 4 + r;
        const int se = g.src[e] - vb, de = g.dst[e] - vb;  // local node ids [0,32)
        float rp = 0.f;
#pragma unroll
        for (int n = 0; n < 2; ++n) {
          float v = acc[m][n][r] + bf2f((uint16_t)a13s[se * 256 + lc[n]]) +
                    bf2f((uint16_t)a13s[de * 256 + 128 + lc[n]]) + bv[n];
          v = fmaxf(v, 0.f);
          rp += v * wv[n];
          // MSG = e_f + visual[src]  (folded; node_reduce reads only MSG)
          g.EF[(size_t)e * 512 + n0g + lc[n]] =
              bfc(v + bf2f((uint16_t)viss[se * 128 + lc[n]]));
        }
        for (int d = 1; d < 16; d <<= 1) rp += __shfl_xor(rp, d);
        if (lr == 0) atomicAdd(&g.AATT[e], rp);
      }
  } else {  // E_PRED
    float bv[2]; int cols[2];
#pragma unroll
    for (int n = 0; n < 2; ++n) { cols[n] = cbase + n * 16 + lr; bv[n] = g.bias[cols[n]]; }
#pragma unroll
    for (int m = 0; m < 4; ++m)
#pragma unroll
      for (int r = 0; r < 4; ++r) {
        const int row = rbase + m * 16 + lg * 4 + r;
        const int te = g.toe[row];
        const int ts = g.src[te], td = g.dst[te];
        const uint16_t* u1 = g.U13 + (size_t)ts * 1024;
        const uint16_t* u3 = g.U13 + (size_t)td * 1024 + 512;
#pragma unroll
        for (int n = 0; n < 2; ++n) {
          const float v = acc[m][n][r] + bf2f(u1[cols[n]]) + bf2f(u3[cols[n]]) + bv[n];
          g.OUT[(size_t)row * 512 + cols[n]] = fmaxf(v, 0.f);
        }
      }
  }
}

// ---- 512-thread BK=64 single-buffer loop, bf16-A via gload_lds, T2 swizzle ----
template <int EPI>
__global__ __launch_bounds__(512, 8) void gemm_lds_k(GemmArgs g) {
  __shared__ __align__(16) short As[8192];
  __shared__ __align__(16) short Bs[8192];
  const int tid = threadIdx.x, w = tid >> 6, lane = tid & 63;

  const int sid = xcd_swz(blockIdx.x, g.nwg);
  const int colb = sid % g.ncol, rowb = sid / g.ncol;
  const int m0 = rowb * BM, n0g = colb * BN;

  const uint16_t* Bp = g.B0; int n0 = n0g;
  if (n0g >= 512) { Bp = g.B1; n0 = n0g - 512; }

  const int r1 = tid >> 3;
  const int sc = ((tid & 7) ^ (r1 & 7)) * 8;   // swizzled src chunk (elems)
  const int d1 = tid * 8;                      // linear LDS dest (shorts)
  const uint16_t* gB1 = Bp + (size_t)(n0 + r1) * g.K + sc;
  const uint16_t* gB2 = gB1 + (size_t)64 * g.K;
  int ga1 = m0 + r1, ga2 = m0 + r1 + 64;
  if (g.gidx) { ga1 = g.gidx[ga1]; ga2 = g.gidx[ga2]; }
  const uint16_t* gA1 = g.Ab + (size_t)ga1 * g.lda + sc;
  const uint16_t* gA2 = g.Ab + (size_t)ga2 * g.lda + sc;

  const int vb = (EPI == E_EDGE) ? (m0 / 240) * 16 : 0;

  const int wm = w >> 2, wn = w & 3;  // 2M x 4N wave grid; wave out = 64x32
  const int lr = lane & 15, lg = lane >> 4;
  int aro[2][4], bro[2][2];
#pragma unroll
  for (int h = 0; h < 2; ++h) {
    const int pc = ((h * 4 + lg) ^ (lr & 7)) * 8;  // swizzled read chunk (shorts)
#pragma unroll
    for (int m = 0; m < 4; ++m) aro[h][m] = (wm * 64 + m * 16 + lr) * 64 + pc;
#pragma unroll
    for (int n = 0; n < 2; ++n) bro[h][n] = (wn * 32 + n * 16 + lr) * 64 + pc;
  }

  f32x4 acc[4][2] = {};

  for (int k0 = 0; k0 < g.K; k0 += 64) {
    __syncthreads();  // LDS reuse guard
    gload_lds16(gB1 + k0, &Bs[d1]);
    gload_lds16(gB2 + k0, &Bs[d1 + 4096]);
    gload_lds16(gA1 + k0, &As[d1]);
    gload_lds16(gA2 + k0, &As[d1 + 4096]);
    __syncthreads();  // stage drained
#pragma unroll
    for (int h = 0; h < 2; ++h) {
      bf16x8 av[4], bv[2];
#pragma unroll
      for (int m = 0; m < 4; ++m) av[m] = *(const bf16x8*)&As[aro[h][m]];
#pragma unroll
      for (int n = 0; n < 2; ++n) bv[n] = *(const bf16x8*)&Bs[bro[h][n]];
#pragma unroll
      for (int m = 0; m < 4; ++m)
#pragma unroll
        for (int n = 0; n < 2; ++n)
          acc[m][n] = __builtin_amdgcn_mfma_f32_16x16x32_bf16(av[m], bv[n], acc[m][n], 0, 0, 0);
    }
  }

  if constexpr (EPI == E_EDGE) {
    __syncthreads();  // all waves done reading As/Bs; reuse for epilogue slices
#pragma unroll
    for (int rd = 0; rd < 2; ++rd) {
      const int idx = rd * 512 + tid;
      const int node = idx >> 5, chunk = idx & 31;
      const int colg = (chunk < 16) ? (n0g + chunk * 8) : (512 + n0g + (chunk - 16) * 8);
      gload_lds16(g.A13 + (size_t)(vb + node) * 1024 + colg, &As[idx * 8]);
    }
    {
      const int node = tid >> 4, chunk = tid & 15;
      gload_lds16(g.VISB + (size_t)(vb + node) * 512 + n0g + chunk * 8, &Bs[tid * 8]);
    }
    __syncthreads();  // slices landed
  }

  gemm_epilogue<EPI>(g, acc, m0, n0g, wm, wn, lr, lg, vb, As, Bs);
}

// ---- fp32-A direct: reg-stage A (4x dwordx4 + 8x cvt_pk + 2x ds_write_b128), B via gload_lds ----
// r14 structure exactly; single change: occupancy hint 6 -> 8 waves/EU (VGPR 36 < 64 cap).
template <int EPI>
__global__ __launch_bounds__(512, 8) void gemm_reg_k(GemmArgs g) {
  __shared__ __align__(16) short As[8192];
  __shared__ __align__(16) short Bs[8192];
  const int tid = threadIdx.x, w = tid >> 6, lane = tid & 63;

  const int sid = xcd_swz(blockIdx.x, g.nwg);
  const int colb = sid % g.ncol, rowb = sid / g.ncol;
  const int m0 = rowb * BM, n0g = colb * BN;

  const uint16_t* Bp = g.B0; int n0 = n0g;
  if (n0g >= 512) { Bp = g.B1; n0 = n0g - 512; }

  const int r1 = tid >> 3;
  const int sc = ((tid & 7) ^ (r1 & 7)) * 8;   // swizzled src chunk (elems)
  const int d1 = tid * 8;                      // LDS dest (shorts)
  const uint16_t* gB1 = Bp + (size_t)(n0 + r1) * g.K + sc;
  const uint16_t* gB2 = gB1 + (size_t)64 * g.K;
  int ga1 = m0 + r1, ga2 = m0 + r1 + 64;
  if (g.gidx) { ga1 = g.gidx[ga1]; ga2 = g.gidx[ga2]; }
  const float* fA1 = g.Af + (size_t)ga1 * 512 + sc;
  const float* fA2 = g.Af + (size_t)ga2 * 512 + sc;

  const int vb = (EPI == E_EDGE) ? (m0 / 240) * 16 : 0;

  const int wm = w >> 2, wn = w & 3;
  const int lr = lane & 15, lg = lane >> 4;
  int aro[2][4], bro[2][2];
#pragma unroll
  for (int h = 0; h < 2; ++h) {
    const int pc = ((h * 4 + lg) ^ (lr & 7)) * 8;
#pragma unroll
    for (int m = 0; m < 4; ++m) aro[h][m] = (wm * 64 + m * 16 + lr) * 64 + pc;
#pragma unroll
    for (int n = 0; n < 2; ++n) bro[h][n] = (wn * 32 + n * 16 + lr) * 64 + pc;
  }

  f32x4 acc[4][2] = {};

  for (int k0 = 0; k0 < g.K; k0 += 64) {
    __syncthreads();  // LDS reuse guard
    gload_lds16(gB1 + k0, &Bs[d1]);
    gload_lds16(gB2 + k0, &Bs[d1 + 4096]);
    const float4 a0 = *(const float4*)(fA1 + k0);
    const float4 a1 = *(const float4*)(fA1 + k0 + 4);
    const float4 b0 = *(const float4*)(fA2 + k0);
    const float4 b1 = *(const float4*)(fA2 + k0 + 4);
    u32x4 q1, q2;
    q1[0] = pk2(a0.x, a0.y); q1[1] = pk2(a0.z, a0.w);
    q1[2] = pk2(a1.x, a1.y); q1[3] = pk2(a1.z, a1.w);
    q2[0] = pk2(b0.x, b0.y); q2[1] = pk2(b0.z, b0.w);
    q2[2] = pk2(b1.x, b1.y); q2[3] = pk2(b1.z, b1.w);
    *(u32x4*)&As[d1] = q1;
    *(u32x4*)&As[d1 + 4096] = q2;
    __syncthreads();  // stage drained
#pragma unroll
    for (int h = 0; h < 2; ++h) {
      bf16x8 av[4], bv[2];
#pragma unroll
      for (int m = 0; m < 4; ++m) av[m] = *(const bf16x8*)&As[aro[h][m]];
#pragma unroll
      for (int n = 0; n < 2; ++n) bv[n] = *(const bf16x8*)&Bs[bro[h][n]];
#pragma unroll
      for (int m = 0; m < 4; ++m)
#pragma unroll
        for (int n = 0; n < 2; ++n)
          acc[m][n] = __builtin_amdgcn_mfma_f32_16x16x32_bf16(av[m], bv[n], acc[m][n], 0, 0, 0);
    }
  }

  if constexpr (EPI == E_EDGE) {
    __syncthreads();
#pragma unroll
    for (int rd = 0; rd < 2; ++rd) {
      const int idx = rd * 512 + tid;
      const int node = idx >> 5, chunk = idx & 31;
      const int colg = (chunk < 16) ? (n0g + chunk * 8) : (512 + n0g + (chunk - 16) * 8);
      gload_lds16(g.A13 + (size_t)(vb + node) * 1024 + colg, &As[idx * 8]);
    }
    {
      const int node = tid >> 4, chunk = tid & 15;
      gload_lds16(g.VISB + (size_t)(vb + node) * 512 + n0g + chunk * 8, &Bs[tid * 8]);
    }
    __syncthreads();
  }

  gemm_epilogue<EPI>(g, acc, m0, n0g, wm, wn, lr, lg, vb, As, Bs);
}

// ---------- light prep: cvt vis->VISB+NIN | W transpose | AATT=0 ----------
__global__ __launch_bounds__(256) void prep_k(const float* vis, const float* We,
                                              const float* Wn, const float* Wp,
                                              uint16_t* VISB, uint16_t* NIN,
                                              uint16_t* WT, float* AATT) {
  __shared__ float tile[32][33];
  const int b = blockIdx.x, tid = threadIdx.x;
  if (b < 1024) {               // visual -> VISB + NIN[:,0:512]
    const int base = (b * 256 + tid) * 8;
    const int row = base >> 9, col = base & 511;
    const float4 f0 = *(const float4*)(vis + base);
    const float4 f1 = *(const float4*)(vis + base + 4);
    u32x4 u;
    u[0] = pk2(f0.x, f0.y); u[1] = pk2(f0.z, f0.w);
    u[2] = pk2(f1.x, f1.y); u[3] = pk2(f1.z, f1.w);
    *(u32x4*)(VISB + base) = u;
    *(u32x4*)(NIN + (size_t)row * 1024 + col) = u;
  } else if (b < 3072) {        // weight transpose+cvt: WT[n][k] = bf16(W[k][n])
    const int zb = b - 1024, z = zb >> 8, rem = zb & 255;
    const float* srcp; uint16_t* dstp; int ldo = 512, koff = 0;
    switch (z) {
      default:
      case 0: srcp = We;          dstp = WT;           break;
      case 1: srcp = We + 262144; dstp = WT + 262144;  break;
      case 2: srcp = We + 524288; dstp = WT + 524288;  break;
      case 3: srcp = Wn;          dstp = WT + 786432;  ldo = 1024; break;
      case 4: srcp = Wn + 262144; dstp = WT + 786432;  ldo = 1024; koff = 512; break;
      case 5: srcp = Wp;          dstp = WT + 1310720; break;
      case 6: srcp = Wp + 262144; dstp = WT + 1572864; break;
      case 7: srcp = Wp + 524288; dstp = WT + 1835008; break;
    }
    const int kb = (rem & 15) * 32, nb = (rem >> 4) * 32;
    const int tx = tid & 31, ty = tid >> 5;
#pragma unroll
    for (int s = 0; s < 4; ++s)
      tile[ty + 8 * s][tx] = srcp[(size_t)(kb + ty + 8 * s) * 512 + nb + tx];
    __syncthreads();
#pragma unroll
    for (int s = 0; s < 4; ++s) {
      const int n = nb + ty + 8 * s, k = kb + tx;
      dstp[(size_t)n * ldo + koff + k] = bfc(tile[tx][ty + 8 * s]);
    }
  } else {                      // AATT = 0 (61440 floats, 60 blocks)
    const int i = (b - 3072) * 1024 + tid * 4;
    float4 z4; z4.x = z4.y = z4.z = z4.w = 0.f;
    *(float4*)(AATT + i) = z4;
  }
}

// ---------- softmax over 15 incoming edges + MSG aggregate; writes NIN[:,512:] ----------
__global__ __launch_bounds__(256) void node_reduce_k(const float* AATT, const float* battn,
                                                     const uint16_t* MSG, uint16_t* NIN) {
  const int sub = threadIdx.x >> 7;  // 2 nodes per block
  const int t = threadIdx.x & 127;
  const int v = blockIdx.x * 2 + sub;
  const int gph = v >> 4, j = v & 15;
  __shared__ float sa_s[2][16];
  __shared__ float alf_s[2][16];
  __shared__ int eids_s[2][16];
  if (t < 15) {
    const int i = (t < j) ? t : t + 1;
    const int off = (j < i) ? j : (j - 1);
    const int eid = gph * 240 + i * 15 + off;  // DGL src-major edge id
    eids_s[sub][t] = eid;
    sa_s[sub][t] = fmaxf(AATT[eid] + battn[0], 0.f);
  }
  __syncthreads();
  float mx = -1e30f;
#pragma unroll
  for (int i = 0; i < 15; ++i) mx = fmaxf(mx, sa_s[sub][i]);
  float den = 0.f;
#pragma unroll
  for (int i = 0; i < 15; ++i) den += expf(sa_s[sub][i] - mx);
  if (t < 15) alf_s[sub][t] = expf(sa_s[sub][t] - mx) / den;
  __syncthreads();
  const int c = t * 4;
  float z0 = 0.f, z1 = 0.f, z2 = 0.f, z3 = 0.f;
#pragma unroll
  for (int i = 0; i < 15; ++i) {
    const float a = alf_s[sub][i];
    const ushort4 e4 = *(const ushort4*)(MSG + (size_t)eids_s[sub][i] * 512 + c);
    z0 += a * bf2f(e4.x); z1 += a * bf2f(e4.y);
    z2 += a * bf2f(e4.z); z3 += a * bf2f(e4.w);
  }
  ushort4 o;
  o.x = bfc(z0); o.y = bfc(z1); o.z = bfc(z2); o.w = bfc(z3);
  *(ushort4*)(NIN + (size_t)v * 1024 + 512 + c) = o;
}

// ---------------- launch ----------------
extern "C" void kernel_launch(void* const* d_in, const int* in_sizes, int n_in,
                              void* d_out, int out_size, void* d_ws, size_t ws_size,
                              hipStream_t stream) {
  const float* visual = (const float*)d_in[0];
  const float* spatial = (const float*)d_in[1];
  const float* W_edge = (const float*)d_in[2];
  const float* b_edge = (const float*)d_in[3];
  const float* W_attn = (const float*)d_in[4];
  const float* b_attn = (const float*)d_in[5];
  const float* W_node = (const float*)d_in[6];
  const float* b_node = (const float*)d_in[7];
  const float* W_pred = (const float*)d_in[8];
  const float* b_pred = (const float*)d_in[9];
  const int* src = (const int*)d_in[10];
  const int* dst = (const int*)d_in[11];
  const int* toe = (const int*)d_in[12];
  float* out = (float*)d_out;

  char* ws = (char*)d_ws;
  uint16_t* WT = (uint16_t*)ws;                    // @0        4 MB
  uint16_t* VISB = (uint16_t*)(ws + 4194304);      // @4MB      4 MB
  uint16_t* NIN = (uint16_t*)(ws + 8388608);       // @8MB      8 MB  [4096][1024]
  uint16_t* A13b = (uint16_t*)(ws + 16777216);     // @16MB     8 MB  [4096][1024]
  uint16_t* EF = (uint16_t*)(ws + 25165824);       // @24MB    60 MB  [61440][512]
  float* AATT = (float*)(ws + 88080384);           // @84MB   240 KB
  uint16_t* U13b = A13b;   // A13b dead after edge GEMM
  uint16_t* NNF = EF;      // EF dead after node_reduce

  prep_k<<<3132, 256, 0, stream>>>(visual, W_edge, W_node, W_pred, VISB, NIN, WT, AATT);

  const dim3 blk(512);
  {  // A13 = vis_bf16 @ [W1 | W3]
    GemmArgs a = {};
    a.Ab = VISB; a.lda = 512; a.B0 = WT; a.B1 = WT + 524288; a.K = 512;
    a.nwg = 256; a.ncol = 8;
    a.C16 = A13b; a.ldc = 1024;
    gemm_lds_k<E_PLAIN16><<<256, blk, 0, stream>>>(a);
  }
  {  // MSG = relu(spatial@W2 + A1[src] + A3[dst] + b) + vis[src]; attn partials
    GemmArgs a = {};
    a.Af = spatial; a.B0 = WT + 262144; a.K = 512;
    a.nwg = 1920; a.ncol = 4;
    a.bias = b_edge; a.wattn = W_attn;
    a.src = src; a.dst = dst; a.A13 = A13b; a.VISB = VISB; a.EF = EF; a.AATT = AATT;
    gemm_reg_k<E_EDGE><<<1920, blk, 0, stream>>>(a);
  }
  node_reduce_k<<<2048, 256, 0, stream>>>(AATT, b_attn, EF, NIN);
  {  // new_n_f = relu(NIN @ W_node + b)  (K=1024)
    GemmArgs a = {};
    a.Ab = NIN; a.lda = 1024; a.B0 = WT + 786432; a.K = 1024;
    a.nwg = 128; a.ncol = 4;
    a.bias = b_node; a.C16 = NNF; a.ldc = 512;
    gemm_lds_k<E_NODE><<<128, blk, 0, stream>>>(a);
  }
  {  // U13 = new_n_f @ [Wp1 | Wp3]
    GemmArgs a = {};
    a.Ab = NNF; a.lda = 512; a.B0 = WT + 1310720; a.B1 = WT + 1835008; a.K = 512;
    a.nwg = 256; a.ncol = 8;
    a.C16 = U13b; a.ldc = 1024;
    gemm_lds_k<E_PLAIN16><<<256, blk, 0, stream>>>(a);
  }
  {  // pred = relu(U1[ts] + spatial[toe]@Wp2 + U3[td] + b)
    GemmArgs a = {};
    a.Af = spatial; a.gidx = toe; a.B0 = WT + 1572864; a.K = 512;
    a.nwg = 120; a.ncol = 4;
    a.bias = b_pred; a.toe = toe; a.src = src; a.dst = dst; a.U13 = U13b; a.OUT = out;
    gemm_reg_k<E_PRED><<<120, blk, 0, stream>>>(a);
  }
  (void)in_sizes; (void)n_in; (void)out_size; (void)ws_size;
}

// Round 18
// 156.091 us; speedup vs baseline: 1.1442x; 1.1442x over previous
//
#include <hip/hip_runtime.h>
#include <hip/hip_bf16.h>
#include <stdint.h>

#define BM 128
#define BN 128

typedef __attribute__((ext_vector_type(8))) short bf16x8;
typedef __attribute__((ext_vector_type(4))) float f32x4;
typedef __attribute__((ext_vector_type(4))) uint32_t u32x4;

__device__ __forceinline__ uint32_t pk2(float lo, float hi) {
  union { __hip_bfloat162 h; uint32_t u; } un;
  un.h = __float22bfloat162_rn(make_float2(lo, hi));  // v_cvt_pk_bf16_f32
  return un.u;
}
__device__ __forceinline__ uint16_t bfc(float f) {     // 1-op f32->bf16 RNE
  return (uint16_t)(pk2(f, f) & 0xFFFFu);
}
__device__ __forceinline__ float bf2f(uint16_t s) {
  union { uint32_t u; float f; } v; v.u = ((uint32_t)s) << 16;
  return v.f;
}
__device__ __forceinline__ void gload_lds16(const void* g, void* l) {
  __builtin_amdgcn_global_load_lds((const __attribute__((address_space(1))) void*)g,
                                   (__attribute__((address_space(3))) void*)l, 16, 0, 0);
}
// bijective XCD-chunk swizzle (m204)
__device__ __forceinline__ int xcd_swz(int d, int n) {
  const int q = n >> 3, r = n & 7, x = d & 7, i = d >> 3;
  return (x < r ? x * (q + 1) : r * (q + 1) + (x - r) * q) + i;
}

enum { E_PLAIN16 = 0, E_EDGE = 1, E_NODE = 2, E_PRED = 3 };

struct GemmArgs {
  const uint16_t* Ab; int lda;   // bf16 A (gemm_lds_k)
  const float* Af;               // fp32 A, lda=512 (gemm_reg_k)
  const int* gidx;               // optional row gather
  const uint16_t* B0;            // B^T bf16 [N][K]; out cols < 512
  const uint16_t* B1;            // out cols >= 512
  int K;
  int nwg, ncol;                 // grid decomposition (col-fastest)
  uint16_t* C16; int ldc;        // bf16 output
  const float* bias;
  const float* wattn;
  const int* src; const int* dst; const int* toe;
  const uint16_t* A13;           // bf16 [4096][1024]
  const uint16_t* VISB;          // bf16 [4096][512] (E_EDGE msg fold)
  const uint16_t* U13;           // bf16 [4096][1024]
  uint16_t* EF;                  // MSG bf16 [61440][512]
  float* AATT;                   // attn partials [61440]
  float* OUT;                    // pred fp32 [3840][512]
};

// ---- shared epilogue, 8-wave layout: wave (wm,wn) owns rows wm*64+, cols wn*32+ ----
// C/D frag: col = lane&15, row = (lane>>4)*4 + reg
template <int EPI>
__device__ __forceinline__ void gemm_epilogue(const GemmArgs& g, f32x4 (&acc)[4][2],
                                              int m0, int n0g, int wm, int wn,
                                              int lr, int lg, int vb,
                                              const short* a13s, const short* viss) {
  const int rbase = m0 + wm * 64;
  const int cbase = n0g + wn * 32;
  if constexpr (EPI == E_PLAIN16) {
#pragma unroll
    for (int m = 0; m < 4; ++m)
#pragma unroll
      for (int r = 0; r < 4; ++r) {
        const int row = rbase + m * 16 + lg * 4 + r;
#pragma unroll
        for (int n = 0; n < 2; ++n)
          g.C16[(size_t)row * g.ldc + cbase + n * 16 + lr] = bfc(acc[m][n][r]);
      }
  } else if constexpr (EPI == E_NODE) {
#pragma unroll
    for (int m = 0; m < 4; ++m)
#pragma unroll
      for (int r = 0; r < 4; ++r) {
        const int row = rbase + m * 16 + lg * 4 + r;
#pragma unroll
        for (int n = 0; n < 2; ++n) {
          const int col = cbase + n * 16 + lr;
          g.C16[(size_t)row * g.ldc + col] = bfc(fmaxf(acc[m][n][r] + g.bias[col], 0.f));
        }
      }
  } else if constexpr (EPI == E_EDGE) {
    float bv[2], wv[2]; int lc[2];
#pragma unroll
    for (int n = 0; n < 2; ++n) {
      lc[n] = wn * 32 + n * 16 + lr;          // col within block's 128
      bv[n] = g.bias[n0g + lc[n]];
      wv[n] = g.wattn[n0g + lc[n]];
    }
#pragma unroll
    for (int m = 0; m < 4; ++m)
#pragma unroll
      for (int r = 0; r < 4; ++r) {
        const int e = rbase + m * 16 + lg * 4 + r;
        const int se = g.src[e] - vb, de = g.dst[e] - vb;  // local node ids [0,32)
        float rp = 0.f;
#pragma unroll
        for (int n = 0; n < 2; ++n) {
          float v = acc[m][n][r] + bf2f((uint16_t)a13s[se * 256 + lc[n]]) +
                    bf2f((uint16_t)a13s[de * 256 + 128 + lc[n]]) + bv[n];
          v = fmaxf(v, 0.f);
          rp += v * wv[n];
          // MSG = e_f + visual[src]  (folded; node_reduce reads only MSG)
          g.EF[(size_t)e * 512 + n0g + lc[n]] =
              bfc(v + bf2f((uint16_t)viss[se * 128 + lc[n]]));
        }
        for (int d = 1; d < 16; d <<= 1) rp += __shfl_xor(rp, d);
        if (lr == 0) atomicAdd(&g.AATT[e], rp);
      }
  } else {  // E_PRED
    float bv[2]; int cols[2];
#pragma unroll
    for (int n = 0; n < 2; ++n) { cols[n] = cbase + n * 16 + lr; bv[n] = g.bias[cols[n]]; }
#pragma unroll
    for (int m = 0; m < 4; ++m)
#pragma unroll
      for (int r = 0; r < 4; ++r) {
        const int row = rbase + m * 16 + lg * 4 + r;
        const int te = g.toe[row];
        const int ts = g.src[te], td = g.dst[te];
        const uint16_t* u1 = g.U13 + (size_t)ts * 1024;
        const uint16_t* u3 = g.U13 + (size_t)td * 1024 + 512;
#pragma unroll
        for (int n = 0; n < 2; ++n) {
          const float v = acc[m][n][r] + bf2f(u1[cols[n]]) + bf2f(u3[cols[n]]) + bv[n];
          g.OUT[(size_t)row * 512 + cols[n]] = fmaxf(v, 0.f);
        }
      }
  }
}

// ---- 512-thread BK=64 single-buffer loop, bf16-A via gload_lds, T2 swizzle ----
template <int EPI>
__global__ __launch_bounds__(512, 8) void gemm_lds_k(GemmArgs g) {
  __shared__ __align__(16) short As[8192];
  __shared__ __align__(16) short Bs[8192];
  const int tid = threadIdx.x, w = tid >> 6, lane = tid & 63;

  const int sid = xcd_swz(blockIdx.x, g.nwg);
  const int colb = sid % g.ncol, rowb = sid / g.ncol;
  const int m0 = rowb * BM, n0g = colb * BN;

  const uint16_t* Bp = g.B0; int n0 = n0g;
  if (n0g >= 512) { Bp = g.B1; n0 = n0g - 512; }

  const int r1 = tid >> 3;
  const int sc = ((tid & 7) ^ (r1 & 7)) * 8;   // swizzled src chunk (elems)
  const int d1 = tid * 8;                      // linear LDS dest (shorts)
  const uint16_t* gB1 = Bp + (size_t)(n0 + r1) * g.K + sc;
  const uint16_t* gB2 = gB1 + (size_t)64 * g.K;
  int ga1 = m0 + r1, ga2 = m0 + r1 + 64;
  if (g.gidx) { ga1 = g.gidx[ga1]; ga2 = g.gidx[ga2]; }
  const uint16_t* gA1 = g.Ab + (size_t)ga1 * g.lda + sc;
  const uint16_t* gA2 = g.Ab + (size_t)ga2 * g.lda + sc;

  const int vb = (EPI == E_EDGE) ? (m0 / 240) * 16 : 0;

  const int wm = w >> 2, wn = w & 3;  // 2M x 4N wave grid; wave out = 64x32
  const int lr = lane & 15, lg = lane >> 4;
  int aro[2][4], bro[2][2];
#pragma unroll
  for (int h = 0; h < 2; ++h) {
    const int pc = ((h * 4 + lg) ^ (lr & 7)) * 8;  // swizzled read chunk (shorts)
#pragma unroll
    for (int m = 0; m < 4; ++m) aro[h][m] = (wm * 64 + m * 16 + lr) * 64 + pc;
#pragma unroll
    for (int n = 0; n < 2; ++n) bro[h][n] = (wn * 32 + n * 16 + lr) * 64 + pc;
  }

  f32x4 acc[4][2] = {};

  for (int k0 = 0; k0 < g.K; k0 += 64) {
    __syncthreads();  // LDS reuse guard
    gload_lds16(gB1 + k0, &Bs[d1]);
    gload_lds16(gB2 + k0, &Bs[d1 + 4096]);
    gload_lds16(gA1 + k0, &As[d1]);
    gload_lds16(gA2 + k0, &As[d1 + 4096]);
    __syncthreads();  // stage drained
#pragma unroll
    for (int h = 0; h < 2; ++h) {
      bf16x8 av[4], bv[2];
#pragma unroll
      for (int m = 0; m < 4; ++m) av[m] = *(const bf16x8*)&As[aro[h][m]];
#pragma unroll
      for (int n = 0; n < 2; ++n) bv[n] = *(const bf16x8*)&Bs[bro[h][n]];
#pragma unroll
      for (int m = 0; m < 4; ++m)
#pragma unroll
        for (int n = 0; n < 2; ++n)
          acc[m][n] = __builtin_amdgcn_mfma_f32_16x16x32_bf16(av[m], bv[n], acc[m][n], 0, 0, 0);
    }
  }

  if constexpr (EPI == E_EDGE) {
    __syncthreads();  // all waves done reading As/Bs; reuse for epilogue slices
#pragma unroll
    for (int rd = 0; rd < 2; ++rd) {
      const int idx = rd * 512 + tid;
      const int node = idx >> 5, chunk = idx & 31;
      const int colg = (chunk < 16) ? (n0g + chunk * 8) : (512 + n0g + (chunk - 16) * 8);
      gload_lds16(g.A13 + (size_t)(vb + node) * 1024 + colg, &As[idx * 8]);
    }
    {
      const int node = tid >> 4, chunk = tid & 15;
      gload_lds16(g.VISB + (size_t)(vb + node) * 512 + n0g + chunk * 8, &Bs[tid * 8]);
    }
    __syncthreads();  // slices landed
  }

  gemm_epilogue<EPI>(g, acc, m0, n0g, wm, wn, lr, lg, vb, As, Bs);
}

// ---- fp32-A direct: reg-stage A (4x dwordx4 + 8x cvt_pk + 2x ds_write_b128), B via gload_lds ----
template <int EPI>
__global__ __launch_bounds__(512, 6) void gemm_reg_k(GemmArgs g) {
  __shared__ __align__(16) short As[8192];
  __shared__ __align__(16) short Bs[8192];
  const int tid = threadIdx.x, w = tid >> 6, lane = tid & 63;

  const int sid = xcd_swz(blockIdx.x, g.nwg);
  const int colb = sid % g.ncol, rowb = sid / g.ncol;
  const int m0 = rowb * BM, n0g = colb * BN;

  const uint16_t* Bp = g.B0; int n0 = n0g;
  if (n0g >= 512) { Bp = g.B1; n0 = n0g - 512; }

  const int r1 = tid >> 3;
  const int sc = ((tid & 7) ^ (r1 & 7)) * 8;   // swizzled src chunk (elems)
  const int d1 = tid * 8;                      // LDS dest (shorts)
  const uint16_t* gB1 = Bp + (size_t)(n0 + r1) * g.K + sc;
  const uint16_t* gB2 = gB1 + (size_t)64 * g.K;
  int ga1 = m0 + r1, ga2 = m0 + r1 + 64;
  if (g.gidx) { ga1 = g.gidx[ga1]; ga2 = g.gidx[ga2]; }
  const float* fA1 = g.Af + (size_t)ga1 * 512 + sc;
  const float* fA2 = g.Af + (size_t)ga2 * 512 + sc;

  const int vb = (EPI == E_EDGE) ? (m0 / 240) * 16 : 0;

  const int wm = w >> 2, wn = w & 3;
  const int lr = lane & 15, lg = lane >> 4;
  int aro[2][4], bro[2][2];
#pragma unroll
  for (int h = 0; h < 2; ++h) {
    const int pc = ((h * 4 + lg) ^ (lr & 7)) * 8;
#pragma unroll
    for (int m = 0; m < 4; ++m) aro[h][m] = (wm * 64 + m * 16 + lr) * 64 + pc;
#pragma unroll
    for (int n = 0; n < 2; ++n) bro[h][n] = (wn * 32 + n * 16 + lr) * 64 + pc;
  }

  f32x4 acc[4][2] = {};

  for (int k0 = 0; k0 < g.K; k0 += 64) {
    __syncthreads();  // LDS reuse guard
    gload_lds16(gB1 + k0, &Bs[d1]);
    gload_lds16(gB2 + k0, &Bs[d1 + 4096]);
    const float4 a0 = *(const float4*)(fA1 + k0);
    const float4 a1 = *(const float4*)(fA1 + k0 + 4);
    const float4 b0 = *(const float4*)(fA2 + k0);
    const float4 b1 = *(const float4*)(fA2 + k0 + 4);
    u32x4 q1, q2;
    q1[0] = pk2(a0.x, a0.y); q1[1] = pk2(a0.z, a0.w);
    q1[2] = pk2(a1.x, a1.y); q1[3] = pk2(a1.z, a1.w);
    q2[0] = pk2(b0.x, b0.y); q2[1] = pk2(b0.z, b0.w);
    q2[2] = pk2(b1.x, b1.y); q2[3] = pk2(b1.z, b1.w);
    *(u32x4*)&As[d1] = q1;
    *(u32x4*)&As[d1 + 4096] = q2;
    __syncthreads();  // stage drained
#pragma unroll
    for (int h = 0; h < 2; ++h) {
      bf16x8 av[4], bv[2];
#pragma unroll
      for (int m = 0; m < 4; ++m) av[m] = *(const bf16x8*)&As[aro[h][m]];
#pragma unroll
      for (int n = 0; n < 2; ++n) bv[n] = *(const bf16x8*)&Bs[bro[h][n]];
#pragma unroll
      for (int m = 0; m < 4; ++m)
#pragma unroll
        for (int n = 0; n < 2; ++n)
          acc[m][n] = __builtin_amdgcn_mfma_f32_16x16x32_bf16(av[m], bv[n], acc[m][n], 0, 0, 0);
    }
  }

  if constexpr (EPI == E_EDGE) {
    __syncthreads();
#pragma unroll
    for (int rd = 0; rd < 2; ++rd) {
      const int idx = rd * 512 + tid;
      const int node = idx >> 5, chunk = idx & 31;
      const int colg = (chunk < 16) ? (n0g + chunk * 8) : (512 + n0g + (chunk - 16) * 8);
      gload_lds16(g.A13 + (size_t)(vb + node) * 1024 + colg, &As[idx * 8]);
    }
    {
      const int node = tid >> 4, chunk = tid & 15;
      gload_lds16(g.VISB + (size_t)(vb + node) * 512 + n0g + chunk * 8, &Bs[tid * 8]);
    }
    __syncthreads();
  }

  gemm_epilogue<EPI>(g, acc, m0, n0g, wm, wn, lr, lg, vb, As, Bs);
}

// ---------- light prep: cvt vis->VISB+NIN | W transpose | AATT=0 ----------
__global__ __launch_bounds__(256) void prep_k(const float* vis, const float* We,
                                              const float* Wn, const float* Wp,
                                              uint16_t* VISB, uint16_t* NIN,
                                              uint16_t* WT, float* AATT) {
  __shared__ float tile[32][33];
  const int b = blockIdx.x, tid = threadIdx.x;
  if (b < 1024) {               // visual -> VISB + NIN[:,0:512]
    const int base = (b * 256 + tid) * 8;
    const int row = base >> 9, col = base & 511;
    const float4 f0 = *(const float4*)(vis + base);
    const float4 f1 = *(const float4*)(vis + base + 4);
    u32x4 u;
    u[0] = pk2(f0.x, f0.y); u[1] = pk2(f0.z, f0.w);
    u[2] = pk2(f1.x, f1.y); u[3] = pk2(f1.z, f1.w);
    *(u32x4*)(VISB + base) = u;
    *(u32x4*)(NIN + (size_t)row * 1024 + col) = u;
  } else if (b < 3072) {        // weight transpose+cvt: WT[n][k] = bf16(W[k][n])
    const int zb = b - 1024, z = zb >> 8, rem = zb & 255;
    const float* srcp; uint16_t* dstp; int ldo = 512, koff = 0;
    switch (z) {
      default:
      case 0: srcp = We;          dstp = WT;           break;
      case 1: srcp = We + 262144; dstp = WT + 262144;  break;
      case 2: srcp = We + 524288; dstp = WT + 524288;  break;
      case 3: srcp = Wn;          dstp = WT + 786432;  ldo = 1024; break;
      case 4: srcp = Wn + 262144; dstp = WT + 786432;  ldo = 1024; koff = 512; break;
      case 5: srcp = Wp;          dstp = WT + 1310720; break;
      case 6: srcp = Wp + 262144; dstp = WT + 1572864; break;
      case 7: srcp = Wp + 524288; dstp = WT + 1835008; break;
    }
    const int kb = (rem & 15) * 32, nb = (rem >> 4) * 32;
    const int tx = tid & 31, ty = tid >> 5;
#pragma unroll
    for (int s = 0; s < 4; ++s)
      tile[ty + 8 * s][tx] = srcp[(size_t)(kb + ty + 8 * s) * 512 + nb + tx];
    __syncthreads();
#pragma unroll
    for (int s = 0; s < 4; ++s) {
      const int n = nb + ty + 8 * s, k = kb + tx;
      dstp[(size_t)n * ldo + koff + k] = bfc(tile[tx][ty + 8 * s]);
    }
  } else {                      // AATT = 0 (61440 floats, 60 blocks)
    const int i = (b - 3072) * 1024 + tid * 4;
    float4 z4; z4.x = z4.y = z4.z = z4.w = 0.f;
    *(float4*)(AATT + i) = z4;
  }
}

// ---------- softmax over 15 incoming edges + MSG aggregate; writes NIN[:,512:] ----------
__global__ __launch_bounds__(256) void node_reduce_k(const float* AATT, const float* battn,
                                                     const uint16_t* MSG, uint16_t* NIN) {
  const int sub = threadIdx.x >> 7;  // 2 nodes per block
  const int t = threadIdx.x & 127;
  const int v = blockIdx.x * 2 + sub;
  const int gph = v >> 4, j = v & 15;
  __shared__ float sa_s[2][16];
  __shared__ float alf_s[2][16];
  __shared__ int eids_s[2][16];
  if (t < 15) {
    const int i = (t < j) ? t : t + 1;
    const int off = (j < i) ? j : (j - 1);
    const int eid = gph * 240 + i * 15 + off;  // DGL src-major edge id
    eids_s[sub][t] = eid;
    sa_s[sub][t] = fmaxf(AATT[eid] + battn[0], 0.f);
  }
  __syncthreads();
  float mx = -1e30f;
#pragma unroll
  for (int i = 0; i < 15; ++i) mx = fmaxf(mx, sa_s[sub][i]);
  float den = 0.f;
#pragma unroll
  for (int i = 0; i < 15; ++i) den += expf(sa_s[sub][i] - mx);
  if (t < 15) alf_s[sub][t] = expf(sa_s[sub][t] - mx) / den;
  __syncthreads();
  const int c = t * 4;
  float z0 = 0.f, z1 = 0.f, z2 = 0.f, z3 = 0.f;
#pragma unroll
  for (int i = 0; i < 15; ++i) {
    const float a = alf_s[sub][i];
    const ushort4 e4 = *(const ushort4*)(MSG + (size_t)eids_s[sub][i] * 512 + c);
    z0 += a * bf2f(e4.x); z1 += a * bf2f(e4.y);
    z2 += a * bf2f(e4.z); z3 += a * bf2f(e4.w);
  }
  ushort4 o;
  o.x = bfc(z0); o.y = bfc(z1); o.z = bfc(z2); o.w = bfc(z3);
  *(ushort4*)(NIN + (size_t)v * 1024 + 512 + c) = o;
}

// ---------------- launch ----------------
extern "C" void kernel_launch(void* const* d_in, const int* in_sizes, int n_in,
                              void* d_out, int out_size, void* d_ws, size_t ws_size,
                              hipStream_t stream) {
  const float* visual = (const float*)d_in[0];
  const float* spatial = (const float*)d_in[1];
  const float* W_edge = (const float*)d_in[2];
  const float* b_edge = (const float*)d_in[3];
  const float* W_attn = (const float*)d_in[4];
  const float* b_attn = (const float*)d_in[5];
  const float* W_node = (const float*)d_in[6];
  const float* b_node = (const float*)d_in[7];
  const float* W_pred = (const float*)d_in[8];
  const float* b_pred = (const float*)d_in[9];
  const int* src = (const int*)d_in[10];
  const int* dst = (const int*)d_in[11];
  const int* toe = (const int*)d_in[12];
  float* out = (float*)d_out;

  char* ws = (char*)d_ws;
  uint16_t* WT = (uint16_t*)ws;                    // @0        4 MB
  uint16_t* VISB = (uint16_t*)(ws + 4194304);      // @4MB      4 MB
  uint16_t* NIN = (uint16_t*)(ws + 8388608);       // @8MB      8 MB  [4096][1024]
  uint16_t* A13b = (uint16_t*)(ws + 16777216);     // @16MB     8 MB  [4096][1024]
  uint16_t* EF = (uint16_t*)(ws + 25165824);       // @24MB    60 MB  [61440][512]
  float* AATT = (float*)(ws + 88080384);           // @84MB   240 KB
  uint16_t* U13b = A13b;   // A13b dead after edge GEMM
  uint16_t* NNF = EF;      // EF dead after node_reduce

  prep_k<<<3132, 256, 0, stream>>>(visual, W_edge, W_node, W_pred, VISB, NIN, WT, AATT);

  const dim3 blk(512);
  {  // A13 = vis_bf16 @ [W1 | W3]
    GemmArgs a = {};
    a.Ab = VISB; a.lda = 512; a.B0 = WT; a.B1 = WT + 524288; a.K = 512;
    a.nwg = 256; a.ncol = 8;
    a.C16 = A13b; a.ldc = 1024;
    gemm_lds_k<E_PLAIN16><<<256, blk, 0, stream>>>(a);
  }
  {  // MSG = relu(spatial@W2 + A1[src] + A3[dst] + b) + vis[src]; attn partials
    GemmArgs a = {};
    a.Af = spatial; a.B0 = WT + 262144; a.K = 512;
    a.nwg = 1920; a.ncol = 4;
    a.bias = b_edge; a.wattn = W_attn;
    a.src = src; a.dst = dst; a.A13 = A13b; a.VISB = VISB; a.EF = EF; a.AATT = AATT;
    gemm_reg_k<E_EDGE><<<1920, blk, 0, stream>>>(a);
  }
  node_reduce_k<<<2048, 256, 0, stream>>>(AATT, b_attn, EF, NIN);
  {  // new_n_f = relu(NIN @ W_node + b)  (K=1024)
    GemmArgs a = {};
    a.Ab = NIN; a.lda = 1024; a.B0 = WT + 786432; a.K = 1024;
    a.nwg = 128; a.ncol = 4;
    a.bias = b_node; a.C16 = NNF; a.ldc = 512;
    gemm_lds_k<E_NODE><<<128, blk, 0, stream>>>(a);
  }
  {  // U13 = new_n_f @ [Wp1 | Wp3]
    GemmArgs a = {};
    a.Ab = NNF; a.lda = 512; a.B0 = WT + 1310720; a.B1 = WT + 1835008; a.K = 512;
    a.nwg = 256; a.ncol = 8;
    a.C16 = U13b; a.ldc = 1024;
    gemm_lds_k<E_PLAIN16><<<256, blk, 0, stream>>>(a);
  }
  {  // pred = relu(U1[ts] + spatial[toe]@Wp2 + U3[td] + b)
    GemmArgs a = {};
    a.Af = spatial; a.gidx = toe; a.B0 = WT + 1572864; a.K = 512;
    a.nwg = 120; a.ncol = 4;
    a.bias = b_pred; a.toe = toe; a.src = src; a.dst = dst; a.U13 = U13b; a.OUT = out;
    gemm_reg_k<E_PRED><<<120, blk, 0, stream>>>(a);
  }
  (void)in_sizes; (void)n_in; (void)out_size; (void)ws_size;
}

// Round 19
// 141.128 us; speedup vs baseline: 1.2655x; 1.1060x over previous
//
#include <hip/hip_runtime.h>
#include <hip/hip_bf16.h>
#include <stdint.h>

#define BM 128

typedef __attribute__((ext_vector_type(8))) short bf16x8;
typedef __attribute__((ext_vector_type(4))) float f32x4;
typedef __attribute__((ext_vector_type(4))) uint32_t u32x4;

__device__ __forceinline__ uint32_t pk2(float lo, float hi) {
  union { __hip_bfloat162 h; uint32_t u; } un;
  un.h = __float22bfloat162_rn(make_float2(lo, hi));  // v_cvt_pk_bf16_f32
  return un.u;
}
__device__ __forceinline__ uint16_t bfc(float f) {     // 1-op f32->bf16 RNE
  return (uint16_t)(pk2(f, f) & 0xFFFFu);
}
__device__ __forceinline__ float bf2f(uint16_t s) {
  union { uint32_t u; float f; } v; v.u = ((uint32_t)s) << 16;
  return v.f;
}
__device__ __forceinline__ void gload_lds16(const void* g, void* l) {
  __builtin_amdgcn_global_load_lds((const __attribute__((address_space(1))) void*)g,
                                   (__attribute__((address_space(3))) void*)l, 16, 0, 0);
}
// bijective XCD-chunk swizzle (m204)
__device__ __forceinline__ int xcd_swz(int d, int n) {
  const int q = n >> 3, r = n & 7, x = d & 7, i = d >> 3;
  return (x < r ? x * (q + 1) : r * (q + 1) + (x - r) * q) + i;
}

enum { E_PLAIN16 = 0, E_EDGE = 1, E_NODE = 2, E_PRED = 3 };

struct GemmArgs {
  const uint16_t* Ab; int lda;   // bf16 A (gemm_lds_k)
  const float* Af;               // fp32 A, lda=512 (gemm_reg_k)
  const int* gidx;               // optional row gather
  const uint16_t* B0;            // B^T bf16 [N][K]; out cols < 512
  const uint16_t* B1;            // out cols >= 512
  int K;
  int nwg, ncol;                 // grid decomposition (col-fastest)
  uint16_t* C16; int ldc;        // bf16 output
  const float* bias;
  const float* wattn;
  const int* src; const int* dst; const int* toe;
  const uint16_t* A13;           // bf16 [4096][1024]
  const uint16_t* VISB;          // bf16 [4096][512] (E_EDGE msg fold)
  const uint16_t* U13;           // bf16 [4096][1024]
  uint16_t* EF;                  // MSG bf16 [61440][512]
  float* AATT;                   // attn partials [61440]
  float* OUT;                    // pred fp32 [3840][512]
};

// ==================== bf16-A kernel: BN=128, BK=64, unchanged from r14/r18 ====================
template <int EPI>
__device__ __forceinline__ void gemm_epilogue128(const GemmArgs& g, f32x4 (&acc)[4][2],
                                                 int m0, int n0g, int wm, int wn,
                                                 int lr, int lg) {
  const int rbase = m0 + wm * 64;
  const int cbase = n0g + wn * 32;
  if constexpr (EPI == E_PLAIN16) {
#pragma unroll
    for (int m = 0; m < 4; ++m)
#pragma unroll
      for (int r = 0; r < 4; ++r) {
        const int row = rbase + m * 16 + lg * 4 + r;
#pragma unroll
        for (int n = 0; n < 2; ++n)
          g.C16[(size_t)row * g.ldc + cbase + n * 16 + lr] = bfc(acc[m][n][r]);
      }
  } else {  // E_NODE
#pragma unroll
    for (int m = 0; m < 4; ++m)
#pragma unroll
      for (int r = 0; r < 4; ++r) {
        const int row = rbase + m * 16 + lg * 4 + r;
#pragma unroll
        for (int n = 0; n < 2; ++n) {
          const int col = cbase + n * 16 + lr;
          g.C16[(size_t)row * g.ldc + col] = bfc(fmaxf(acc[m][n][r] + g.bias[col], 0.f));
        }
      }
  }
}

template <int EPI>
__global__ __launch_bounds__(512, 8) void gemm_lds_k(GemmArgs g) {
  __shared__ __align__(16) short As[8192];
  __shared__ __align__(16) short Bs[8192];
  const int tid = threadIdx.x, w = tid >> 6, lane = tid & 63;

  const int sid = xcd_swz(blockIdx.x, g.nwg);
  const int colb = sid % g.ncol, rowb = sid / g.ncol;
  const int m0 = rowb * BM, n0g = colb * 128;

  const uint16_t* Bp = g.B0; int n0 = n0g;
  if (n0g >= 512) { Bp = g.B1; n0 = n0g - 512; }

  const int r1 = tid >> 3;
  const int sc = ((tid & 7) ^ (r1 & 7)) * 8;   // swizzled src chunk (elems)
  const int d1 = tid * 8;                      // linear LDS dest (shorts)
  const uint16_t* gB1 = Bp + (size_t)(n0 + r1) * g.K + sc;
  const uint16_t* gB2 = gB1 + (size_t)64 * g.K;
  int ga1 = m0 + r1, ga2 = m0 + r1 + 64;
  if (g.gidx) { ga1 = g.gidx[ga1]; ga2 = g.gidx[ga2]; }
  const uint16_t* gA1 = g.Ab + (size_t)ga1 * g.lda + sc;
  const uint16_t* gA2 = g.Ab + (size_t)ga2 * g.lda + sc;

  const int wm = w >> 2, wn = w & 3;  // 2M x 4N wave grid; wave out = 64x32
  const int lr = lane & 15, lg = lane >> 4;
  int aro[2][4], bro[2][2];
#pragma unroll
  for (int h = 0; h < 2; ++h) {
    const int pc = ((h * 4 + lg) ^ (lr & 7)) * 8;  // swizzled read chunk (shorts)
#pragma unroll
    for (int m = 0; m < 4; ++m) aro[h][m] = (wm * 64 + m * 16 + lr) * 64 + pc;
#pragma unroll
    for (int n = 0; n < 2; ++n) bro[h][n] = (wn * 32 + n * 16 + lr) * 64 + pc;
  }

  f32x4 acc[4][2] = {};

  for (int k0 = 0; k0 < g.K; k0 += 64) {
    __syncthreads();  // LDS reuse guard
    gload_lds16(gB1 + k0, &Bs[d1]);
    gload_lds16(gB2 + k0, &Bs[d1 + 4096]);
    gload_lds16(gA1 + k0, &As[d1]);
    gload_lds16(gA2 + k0, &As[d1 + 4096]);
    __syncthreads();  // stage drained
#pragma unroll
    for (int h = 0; h < 2; ++h) {
      bf16x8 av[4], bv[2];
#pragma unroll
      for (int m = 0; m < 4; ++m) av[m] = *(const bf16x8*)&As[aro[h][m]];
#pragma unroll
      for (int n = 0; n < 2; ++n) bv[n] = *(const bf16x8*)&Bs[bro[h][n]];
#pragma unroll
      for (int m = 0; m < 4; ++m)
#pragma unroll
        for (int n = 0; n < 2; ++n)
          acc[m][n] = __builtin_amdgcn_mfma_f32_16x16x32_bf16(av[m], bv[n], acc[m][n], 0, 0, 0);
    }
  }

  gemm_epilogue128<EPI>(g, acc, m0, n0g, wm, wn, lr, lg);
}

// ==================== fp32-A kernel: BN=256, BK=64 (arithmetic-intensity x2) ====================
// LDS: Bs 256x64 (32KB) + As 128x64 (16KB) = 48KB. Wave out = 64x64 (acc[4][4]).
// Staged bytes per output halve vs BN=128 -> less L2->LDS volume, fewer A re-reads.
// E_EDGE epilogue slices reuse the pool post-loop: a13 (32KB) -> Bs, vis (16KB) -> As.
template <int EPI>
__global__ __launch_bounds__(512, 4) void gemm_reg_k(GemmArgs g) {
  __shared__ __align__(16) short As[8192];   // A tile / vis slice
  __shared__ __align__(16) short Bs[16384];  // B tile / a13 slice
  const int tid = threadIdx.x, w = tid >> 6, lane = tid & 63;

  const int sid = xcd_swz(blockIdx.x, g.nwg);
  const int colb = sid % g.ncol, rowb = sid / g.ncol;
  const int m0 = rowb * BM, n0g = colb * 256;

  const uint16_t* Bp = g.B0;  // N=512 for both users; n0g in {0,256}

  const int r1 = tid >> 3;                     // 0..63
  const int sc = ((tid & 7) ^ (r1 & 7)) * 8;   // swizzled src chunk (elems)
  const int d1 = tid * 8;                      // LDS dest (shorts)
  const uint16_t* gB[4];
#pragma unroll
  for (int s = 0; s < 4; ++s) gB[s] = Bp + (size_t)(n0g + r1 + s * 64) * g.K + sc;
  int ga1 = m0 + r1, ga2 = m0 + r1 + 64;
  if (g.gidx) { ga1 = g.gidx[ga1]; ga2 = g.gidx[ga2]; }
  const float* fA1 = g.Af + (size_t)ga1 * 512 + sc;
  const float* fA2 = g.Af + (size_t)ga2 * 512 + sc;

  const int vb = (EPI == E_EDGE) ? (m0 / 240) * 16 : 0;

  const int wm = w >> 2, wn = w & 3;  // 2M x 4N wave grid; wave out = 64x64
  const int lr = lane & 15, lg = lane >> 4;
  int aro[2][4], bro[2][4];
#pragma unroll
  for (int h = 0; h < 2; ++h) {
    const int pc = ((h * 4 + lg) ^ (lr & 7)) * 8;
#pragma unroll
    for (int m = 0; m < 4; ++m) aro[h][m] = (wm * 64 + m * 16 + lr) * 64 + pc;
#pragma unroll
    for (int n = 0; n < 4; ++n) bro[h][n] = (wn * 64 + n * 16 + lr) * 64 + pc;
  }

  f32x4 acc[4][4] = {};

  for (int k0 = 0; k0 < g.K; k0 += 64) {
    __syncthreads();  // LDS reuse guard
#pragma unroll
    for (int s = 0; s < 4; ++s) gload_lds16(gB[s] + k0, &Bs[d1 + s * 4096]);
    const float4 a0 = *(const float4*)(fA1 + k0);
    const float4 a1 = *(const float4*)(fA1 + k0 + 4);
    const float4 b0 = *(const float4*)(fA2 + k0);
    const float4 b1 = *(const float4*)(fA2 + k0 + 4);
    u32x4 q1, q2;
    q1[0] = pk2(a0.x, a0.y); q1[1] = pk2(a0.z, a0.w);
    q1[2] = pk2(a1.x, a1.y); q1[3] = pk2(a1.z, a1.w);
    q2[0] = pk2(b0.x, b0.y); q2[1] = pk2(b0.z, b0.w);
    q2[2] = pk2(b1.x, b1.y); q2[3] = pk2(b1.z, b1.w);
    *(u32x4*)&As[d1] = q1;
    *(u32x4*)&As[d1 + 4096] = q2;
    __syncthreads();  // stage drained
#pragma unroll
    for (int h = 0; h < 2; ++h) {
      bf16x8 av[4], bv[4];
#pragma unroll
      for (int m = 0; m < 4; ++m) av[m] = *(const bf16x8*)&As[aro[h][m]];
#pragma unroll
      for (int n = 0; n < 4; ++n) bv[n] = *(const bf16x8*)&Bs[bro[h][n]];
#pragma unroll
      for (int m = 0; m < 4; ++m)
#pragma unroll
        for (int n = 0; n < 4; ++n)
          acc[m][n] = __builtin_amdgcn_mfma_f32_16x16x32_bf16(av[m], bv[n], acc[m][n], 0, 0, 0);
    }
  }

  // ---- epilogue ----  C/D frag: col = lane&15, row = (lane>>4)*4 + reg
  const int rbase = m0 + wm * 64;

  if constexpr (EPI == E_EDGE) {
    __syncthreads();  // GEMM reads done; reuse pool
    // a13 slices: 32 nodes x (256 A1-cols | 256 A3-cols) -> Bs [node*512 + half*256 + c]
#pragma unroll
    for (int rd = 0; rd < 4; ++rd) {
      const int idx = rd * 512 + tid;          // 0..2047 chunks
      const int node = idx >> 6, chunk = idx & 63;
      const int colg = (chunk < 32) ? (n0g + chunk * 8) : (512 + n0g + (chunk - 32) * 8);
      gload_lds16(g.A13 + (size_t)(vb + node) * 1024 + colg, &Bs[idx * 8]);
    }
    // vis slices: 32 nodes x 256 cols -> As [node*256 + c]
#pragma unroll
    for (int rd = 0; rd < 2; ++rd) {
      const int idx = rd * 512 + tid;          // 0..1023 chunks
      const int node = idx >> 5, chunk = idx & 31;
      gload_lds16(g.VISB + (size_t)(vb + node) * 512 + n0g + chunk * 8, &As[idx * 8]);
    }
    __syncthreads();  // slices landed

    float bv[4], wv[4]; int lc[4];
#pragma unroll
    for (int n = 0; n < 4; ++n) {
      lc[n] = wn * 64 + n * 16 + lr;           // col within block's 256
      bv[n] = g.bias[n0g + lc[n]];
      wv[n] = g.wattn[n0g + lc[n]];
    }
#pragma unroll
    for (int m = 0; m < 4; ++m)
#pragma unroll
      for (int r = 0; r < 4; ++r) {
        const int e = rbase + m * 16 + lg * 4 + r;
        const int se = g.src[e] - vb, de = g.dst[e] - vb;
        float rp = 0.f;
#pragma unroll
        for (int n = 0; n < 4; ++n) {
          float v = acc[m][n][r] + bf2f((uint16_t)Bs[se * 512 + lc[n]]) +
                    bf2f((uint16_t)Bs[de * 512 + 256 + lc[n]]) + bv[n];
          v = fmaxf(v, 0.f);
          rp += v * wv[n];
          // MSG = e_f + visual[src]
          g.EF[(size_t)e * 512 + n0g + lc[n]] =
              bfc(v + bf2f((uint16_t)As[se * 256 + lc[n]]));
        }
        for (int d = 1; d < 16; d <<= 1) rp += __shfl_xor(rp, d);
        if (lr == 0) atomicAdd(&g.AATT[e], rp);
      }
  } else {  // E_PRED
    float bv[4]; int cols[4];
#pragma unroll
    for (int n = 0; n < 4; ++n) {
      cols[n] = n0g + wn * 64 + n * 16 + lr;
      bv[n] = g.bias[cols[n]];
    }
#pragma unroll
    for (int m = 0; m < 4; ++m)
#pragma unroll
      for (int r = 0; r < 4; ++r) {
        const int row = rbase + m * 16 + lg * 4 + r;
        const int te = g.toe[row];
        const int ts = g.src[te], td = g.dst[te];
        const uint16_t* u1 = g.U13 + (size_t)ts * 1024;
        const uint16_t* u3 = g.U13 + (size_t)td * 1024 + 512;
#pragma unroll
        for (int n = 0; n < 4; ++n) {
          const float v = acc[m][n][r] + bf2f(u1[cols[n]]) + bf2f(u3[cols[n]]) + bv[n];
          g.OUT[(size_t)row * 512 + cols[n]] = fmaxf(v, 0.f);
        }
      }
  }
}

// ---------- light prep: cvt vis->VISB+NIN | W transpose | AATT=0 ----------
__global__ __launch_bounds__(256) void prep_k(const float* vis, const float* We,
                                              const float* Wn, const float* Wp,
                                              uint16_t* VISB, uint16_t* NIN,
                                              uint16_t* WT, float* AATT) {
  __shared__ float tile[32][33];
  const int b = blockIdx.x, tid = threadIdx.x;
  if (b < 1024) {               // visual -> VISB + NIN[:,0:512]
    const int base = (b * 256 + tid) * 8;
    const int row = base >> 9, col = base & 511;
    const float4 f0 = *(const float4*)(vis + base);
    const float4 f1 = *(const float4*)(vis + base + 4);
    u32x4 u;
    u[0] = pk2(f0.x, f0.y); u[1] = pk2(f0.z, f0.w);
    u[2] = pk2(f1.x, f1.y); u[3] = pk2(f1.z, f1.w);
    *(u32x4*)(VISB + base) = u;
    *(u32x4*)(NIN + (size_t)row * 1024 + col) = u;
  } else if (b < 3072) {        // weight transpose+cvt: WT[n][k] = bf16(W[k][n])
    const int zb = b - 1024, z = zb >> 8, rem = zb & 255;
    const float* srcp; uint16_t* dstp; int ldo = 512, koff = 0;
    switch (z) {
      default:
      case 0: srcp = We;          dstp = WT;           break;
      case 1: srcp = We + 262144; dstp = WT + 262144;  break;
      case 2: srcp = We + 524288; dstp = WT + 524288;  break;
      case 3: srcp = Wn;          dstp = WT + 786432;  ldo = 1024; break;
      case 4: srcp = Wn + 262144; dstp = WT + 786432;  ldo = 1024; koff = 512; break;
      case 5: srcp = Wp;          dstp = WT + 1310720; break;
      case 6: srcp = Wp + 262144; dstp = WT + 1572864; break;
      case 7: srcp = Wp + 524288; dstp = WT + 1835008; break;
    }
    const int kb = (rem & 15) * 32, nb = (rem >> 4) * 32;
    const int tx = tid & 31, ty = tid >> 5;
#pragma unroll
    for (int s = 0; s < 4; ++s)
      tile[ty + 8 * s][tx] = srcp[(size_t)(kb + ty + 8 * s) * 512 + nb + tx];
    __syncthreads();
#pragma unroll
    for (int s = 0; s < 4; ++s) {
      const int n = nb + ty + 8 * s, k = kb + tx;
      dstp[(size_t)n * ldo + koff + k] = bfc(tile[tx][ty + 8 * s]);
    }
  } else {                      // AATT = 0 (61440 floats, 60 blocks)
    const int i = (b - 3072) * 1024 + tid * 4;
    float4 z4; z4.x = z4.y = z4.z = z4.w = 0.f;
    *(float4*)(AATT + i) = z4;
  }
}

// ---------- softmax over 15 incoming edges + MSG aggregate; writes NIN[:,512:] ----------
__global__ __launch_bounds__(256) void node_reduce_k(const float* AATT, const float* battn,
                                                     const uint16_t* MSG, uint16_t* NIN) {
  const int sub = threadIdx.x >> 7;  // 2 nodes per block
  const int t = threadIdx.x & 127;
  const int v = blockIdx.x * 2 + sub;
  const int gph = v >> 4, j = v & 15;
  __shared__ float sa_s[2][16];
  __shared__ float alf_s[2][16];
  __shared__ int eids_s[2][16];
  if (t < 15) {
    const int i = (t < j) ? t : t + 1;
    const int off = (j < i) ? j : (j - 1);
    const int eid = gph * 240 + i * 15 + off;  // DGL src-major edge id
    eids_s[sub][t] = eid;
    sa_s[sub][t] = fmaxf(AATT[eid] + battn[0], 0.f);
  }
  __syncthreads();
  float mx = -1e30f;
#pragma unroll
  for (int i = 0; i < 15; ++i) mx = fmaxf(mx, sa_s[sub][i]);
  float den = 0.f;
#pragma unroll
  for (int i = 0; i < 15; ++i) den += expf(sa_s[sub][i] - mx);
  if (t < 15) alf_s[sub][t] = expf(sa_s[sub][t] - mx) / den;
  __syncthreads();
  const int c = t * 4;
  float z0 = 0.f, z1 = 0.f, z2 = 0.f, z3 = 0.f;
#pragma unroll
  for (int i = 0; i < 15; ++i) {
    const float a = alf_s[sub][i];
    const ushort4 e4 = *(const ushort4*)(MSG + (size_t)eids_s[sub][i] * 512 + c);
    z0 += a * bf2f(e4.x); z1 += a * bf2f(e4.y);
    z2 += a * bf2f(e4.z); z3 += a * bf2f(e4.w);
  }
  ushort4 o;
  o.x = bfc(z0); o.y = bfc(z1); o.z = bfc(z2); o.w = bfc(z3);
  *(ushort4*)(NIN + (size_t)v * 1024 + 512 + c) = o;
}

// ---------------- launch ----------------
extern "C" void kernel_launch(void* const* d_in, const int* in_sizes, int n_in,
                              void* d_out, int out_size, void* d_ws, size_t ws_size,
                              hipStream_t stream) {
  const float* visual = (const float*)d_in[0];
  const float* spatial = (const float*)d_in[1];
  const float* W_edge = (const float*)d_in[2];
  const float* b_edge = (const float*)d_in[3];
  const float* W_attn = (const float*)d_in[4];
  const float* b_attn = (const float*)d_in[5];
  const float* W_node = (const float*)d_in[6];
  const float* b_node = (const float*)d_in[7];
  const float* W_pred = (const float*)d_in[8];
  const float* b_pred = (const float*)d_in[9];
  const int* src = (const int*)d_in[10];
  const int* dst = (const int*)d_in[11];
  const int* toe = (const int*)d_in[12];
  float* out = (float*)d_out;

  char* ws = (char*)d_ws;
  uint16_t* WT = (uint16_t*)ws;                    // @0        4 MB
  uint16_t* VISB = (uint16_t*)(ws + 4194304);      // @4MB      4 MB
  uint16_t* NIN = (uint16_t*)(ws + 8388608);       // @8MB      8 MB  [4096][1024]
  uint16_t* A13b = (uint16_t*)(ws + 16777216);     // @16MB     8 MB  [4096][1024]
  uint16_t* EF = (uint16_t*)(ws + 25165824);       // @24MB    60 MB  [61440][512]
  float* AATT = (float*)(ws + 88080384);           // @84MB   240 KB
  uint16_t* U13b = A13b;   // A13b dead after edge GEMM
  uint16_t* NNF = EF;      // EF dead after node_reduce

  prep_k<<<3132, 256, 0, stream>>>(visual, W_edge, W_node, W_pred, VISB, NIN, WT, AATT);

  const dim3 blk(512);
  {  // A13 = vis_bf16 @ [W1 | W3]
    GemmArgs a = {};
    a.Ab = VISB; a.lda = 512; a.B0 = WT; a.B1 = WT + 524288; a.K = 512;
    a.nwg = 256; a.ncol = 8;
    a.C16 = A13b; a.ldc = 1024;
    gemm_lds_k<E_PLAIN16><<<256, blk, 0, stream>>>(a);
  }
  {  // MSG = relu(spatial@W2 + A1[src] + A3[dst] + b) + vis[src]; attn partials
    GemmArgs a = {};
    a.Af = spatial; a.B0 = WT + 262144; a.K = 512;
    a.nwg = 960; a.ncol = 2;   // BN=256
    a.bias = b_edge; a.wattn = W_attn;
    a.src = src; a.dst = dst; a.A13 = A13b; a.VISB = VISB; a.EF = EF; a.AATT = AATT;
    gemm_reg_k<E_EDGE><<<960, blk, 0, stream>>>(a);
  }
  node_reduce_k<<<2048, 256, 0, stream>>>(AATT, b_attn, EF, NIN);
  {  // new_n_f = relu(NIN @ W_node + b)  (K=1024)
    GemmArgs a = {};
    a.Ab = NIN; a.lda = 1024; a.B0 = WT + 786432; a.K = 1024;
    a.nwg = 128; a.ncol = 4;
    a.bias = b_node; a.C16 = NNF; a.ldc = 512;
    gemm_lds_k<E_NODE><<<128, blk, 0, stream>>>(a);
  }
  {  // U13 = new_n_f @ [Wp1 | Wp3]
    GemmArgs a = {};
    a.Ab = NNF; a.lda = 512; a.B0 = WT + 1310720; a.B1 = WT + 1835008; a.K = 512;
    a.nwg = 256; a.ncol = 8;
    a.C16 = U13b; a.ldc = 1024;
    gemm_lds_k<E_PLAIN16><<<256, blk, 0, stream>>>(a);
  }
  {  // pred = relu(U1[ts] + spatial[toe]@Wp2 + U3[td] + b)
    GemmArgs a = {};
    a.Af = spatial; a.gidx = toe; a.B0 = WT + 1572864; a.K = 512;
    a.nwg = 60; a.ncol = 2;    // BN=256
    a.bias = b_pred; a.toe = toe; a.src = src; a.dst = dst; a.U13 = U13b; a.OUT = out;
    gemm_reg_k<E_PRED><<<60, blk, 0, stream>>>(a);
  }
  (void)in_sizes; (void)n_in; (void)out_size; (void)ws_size;
}